// Round 13
// baseline (214.000 us; speedup 1.0000x reference)
//
#include <hip/hip_runtime.h>

// MHSA: B=4, N=2048, C=1024, H=16, HD=64
// cast(f32->bf16) -> GEMM1 (qkv, Q pre-scaled by 0.125*log2e) -> flash attn (swapped 32x32) -> GEMM2 (+bias)

typedef float f32x2 __attribute__((ext_vector_type(2)));
typedef float f32x4 __attribute__((ext_vector_type(4)));
typedef float f32x16 __attribute__((ext_vector_type(16)));
typedef __bf16 bf16x8 __attribute__((ext_vector_type(8)));
typedef __bf16 bf16x4 __attribute__((ext_vector_type(4)));
typedef __bf16 bf16x2 __attribute__((ext_vector_type(2)));
typedef unsigned int u32;
typedef unsigned int u32x2 __attribute__((ext_vector_type(2)));

__device__ __forceinline__ void async16(const void* g, void* l) {
  __builtin_amdgcn_global_load_lds((const __attribute__((address_space(1))) unsigned int*)g,
                                   (__attribute__((address_space(3))) unsigned int*)l, 16, 0, 0);
}
__device__ __forceinline__ u32 cvtpk_bf16(float lo, float hi) {
  u32 r;
  asm("v_cvt_pk_bf16_f32 %0, %1, %2" : "=v"(r) : "v"(lo), "v"(hi));
  return r;
}
// v_permlane32_swap_b32 a, b : a.row1 <-> b.row0. Only with DISTINCT sources (never self-swap).
__device__ __forceinline__ void swap32(u32& a, u32& b) {
  asm volatile("v_permlane32_swap_b32 %0, %1" : "+v"(a), "+v"(b));
}
__device__ __forceinline__ float xmax64(float x) { return fmaxf(x, __shfl_xor(x, 32, 64)); }
__device__ __forceinline__ float exp2v(float x) { return __builtin_amdgcn_exp2f(x); }
__device__ __forceinline__ f32x2 pkmax(f32x2 a, f32x2 b) {
  return f32x2{ fmaxf(a.x, b.x), fmaxf(a.y, b.y) };
}

// ---------------- cast: x, w_qkv, w_proj f32 -> bf16 ----------------
__global__ __launch_bounds__(256) void cast_to_bf16(const float* __restrict__ x,
                                                    const float* __restrict__ wq,
                                                    const float* __restrict__ wp,
                                                    __bf16* __restrict__ xo,
                                                    __bf16* __restrict__ wqo,
                                                    __bf16* __restrict__ wpo) {
  long i = (long)blockIdx.x * 256 + threadIdx.x;
  const float* s; __bf16* d; long j;
  if (i < 2097152L)      { s = x;  d = xo;  j = i; }
  else if (i < 2883584L) { s = wq; d = wqo; j = i - 2097152L; }
  else                   { s = wp; d = wpo; j = i - 2883584L; }
  float4 v = ((const float4*)s)[j];
  bf16x4 o = { (__bf16)v.x, (__bf16)v.y, (__bf16)v.z, (__bf16)v.w };
  ((bf16x4*)d)[j] = o;
}

// ---------------- GEMM (B^T), m97 structure (verified R1/R3/R10) + T1 XCD swizzle ----------------
// R13: reverted from R12's counted-vmcnt ring (regressed ~4us — T4 needs 8-phase interleave,
// confirmed regime-gate). Block mapping XCD-swizzled: each XCD owns a contiguous bn-chunk so
// its 128-col B-panel (256KB) stays L2-resident across the bm sweep. Bijective (nwg%8==0).
template <int EPI>
__global__ __launch_bounds__(256) void gemm_bt(const __bf16* __restrict__ A,
                                               const __bf16* __restrict__ Bw,
                                               __bf16* __restrict__ Oq,
                                               float* __restrict__ Of,
                                               const float* __restrict__ bias) {
  const int tid = threadIdx.x;
  const int lane = tid & 63, w = tid >> 6;
  const int arow = lane & 15, agrp = lane >> 4;
  const int wm = w >> 1, wn = w & 1;
  // T1 XCD swizzle (bijective: gridDim.x*gridDim.y % 8 == 0; both launches use gridDim.x=64)
  int id = blockIdx.y * gridDim.x + blockIdx.x;
  const int cpx = (gridDim.x * gridDim.y) >> 3;
  id = (id & 7) * cpx + (id >> 3);
  const int bm = id & 63, bn = id >> 6;
  __shared__ __bf16 As[128 * 32];
  __shared__ __bf16 Bs[128 * 32];
  f32x4 acc[4][4] = {};

  const int c0 = tid, c1 = tid + 256;
  const __bf16* Ag0 = A + ((size_t)(bm * 128 + (c0 >> 2)) << 10) + (c0 & 3) * 8;
  const __bf16* Ag1 = A + ((size_t)(bm * 128 + (c1 >> 2)) << 10) + (c1 & 3) * 8;
  const __bf16* Bg0 = Bw + ((size_t)(bn * 128 + (c0 >> 2)) << 10) + (c0 & 3) * 8;
  const __bf16* Bg1 = Bw + ((size_t)(bn * 128 + (c1 >> 2)) << 10) + (c1 & 3) * 8;

  for (int kt = 0; kt < 1024; kt += 32) {
    async16(Ag0 + kt, &As[c0 * 8]);
    async16(Ag1 + kt, &As[c1 * 8]);
    async16(Bg0 + kt, &Bs[c0 * 8]);
    async16(Bg1 + kt, &Bs[c1 * 8]);
    __syncthreads();
    bf16x8 af[4], bfr[4];
#pragma unroll
    for (int mi = 0; mi < 4; ++mi)
      af[mi] = *(const bf16x8*)&As[(wm * 64 + mi * 16 + arow) * 32 + agrp * 8];
#pragma unroll
    for (int ni = 0; ni < 4; ++ni)
      bfr[ni] = *(const bf16x8*)&Bs[(wn * 64 + ni * 16 + arow) * 32 + agrp * 8];
#pragma unroll
    for (int mi = 0; mi < 4; ++mi)
#pragma unroll
      for (int ni = 0; ni < 4; ++ni)
        acc[mi][ni] = __builtin_amdgcn_mfma_f32_16x16x32_bf16(af[mi], bfr[ni], acc[mi][ni], 0, 0, 0);
    __syncthreads();
  }

  const int rowb = bm * 128 + wm * 64 + agrp * 4;
  const int colb = bn * 128 + wn * 64 + arow;
  if (EPI == 0) {
#pragma unroll
    for (int mi = 0; mi < 4; ++mi) {
      const int row = rowb + mi * 16;
      const int bidx = row >> 11;
#pragma unroll
      for (int ni = 0; ni < 4; ++ni) {
        f32x4 v = acc[mi][ni];
        const int col = colb + ni * 16;
        const int which = col >> 10;
        const int h = (col >> 6) & 15;
        const int hd = col & 63;
        // Q pre-scale: 0.125 * log2(e) so attn softmax runs in exp2 domain
        const float s = (which == 0) ? 0.18033688011112042f : 1.0f;
        __bf16* dst = Oq + ((size_t)which * 64 + bidx * 16 + h) * (size_t)(2048 * 64) + hd;
#pragma unroll
        for (int i = 0; i < 4; ++i)
          dst[(size_t)((row + i) & 2047) * 64] = (__bf16)(v[i] * s);
      }
    }
  } else {
#pragma unroll
    for (int mi = 0; mi < 4; ++mi) {
      const int row = rowb + mi * 16;
#pragma unroll
      for (int ni = 0; ni < 4; ++ni) {
        const int col = colb + ni * 16;
        const float bv = bias[col];
        f32x4 v = acc[mi][ni];
#pragma unroll
        for (int i = 0; i < 4; ++i)
          Of[(size_t)(row + i) * 1024 + col] = v[i] + bv;
      }
    }
  }
}

// ---------------- flash attention (R10, verified: 117.5us) ----------------
// At its structural LDS-port roofline: MfmaUtil 31% == port cap for 20 MFMA : 16 b128-reads/iter.
__global__ __launch_bounds__(256) void mhsa_attn(const __bf16* __restrict__ QKV,
                                                 __bf16* __restrict__ Out) {
  const int tid = threadIdx.x;
  const int lane = tid & 63, w = tid >> 6;
  const int blk = blockIdx.x;           // blk = qt*64 + bh -> XCD(blk%8)=bh%8: KV L2-resident per XCD
  const int bh = blk & 63, qt = blk >> 6;
  const int lq = lane & 31, hi = lane >> 5;
  const int l7 = lane & 7, l3 = lane >> 3;

  const size_t bhoff = (size_t)bh * (2048 * 64);
  const __bf16* Qp = QKV + bhoff;
  const __bf16* Kp = QKV + (size_t)(64 * 2048 * 64) + bhoff;
  const __bf16* Vp = QKV + (size_t)(128 * 2048 * 64) + bhoff;

  __shared__ char smem[32768];  // 2 x {K [64][64] swz (8KB) | V^T [64][64] swz (8KB)}

  const int q0 = qt * 128 + w * 32;

  bf16x8 qf[4];
#pragma unroll
  for (int s = 0; s < 4; ++s)
    qf[s] = *(const bf16x8*)&Qp[(size_t)(q0 + lq) * 64 + s * 16 + hi * 8];

  // all-ones bf16 A-operand for the l-MFMA (layout-invariant)
  union { u32 wv[4]; bf16x8 v; } ou;
  ou.wv[0] = ou.wv[1] = ou.wv[2] = ou.wv[3] = 0x3F803F80u;
  const bf16x8 onesA = ou.v;

  f32x16 Oacc0 = 0.f, Oacc1 = 0.f;   // OT: col=lane&31=q, d(per 32-blk)=(r&3)+8*(r>>2)+4*hi
  f32x16 lacc = 0.f;                 // l accumulator: every row = sum_k P[k][q=lq]
  float m_run = -1e30f;

  const __bf16* Kg = Kp + (size_t)(w * 16 + l3) * 64 + ((l7 ^ l3) * 8);
  const int kldoff = w * 2048 + lane * 16;

  const int c8v = tid >> 5, k0v = (tid & 31) * 2;

  // ---- prologue: stage tile 0 into buf0 ----
  {
    async16(Kg, smem + kldoff);
    async16(Kg + 512, smem + kldoff + 1024);
    bf16x8 v0 = *(const bf16x8*)&Vp[(size_t)k0v * 64 + c8v * 8];
    bf16x8 v1 = *(const bf16x8*)&Vp[(size_t)(k0v + 1) * 64 + c8v * 8];
    char* Vb = smem + 8192;
#pragma unroll
    for (int j = 0; j < 8; ++j) {
      const int d = c8v * 8 + j;
      bf16x2 pr = { v0[j], v1[j] };
      *(bf16x2*)(Vb + ((d * 128 + k0v * 2) ^ ((d & 7) << 4))) = pr;
    }
  }
  __syncthreads();  // drains vmcnt -> K tile0 resident

  for (int t = 0; t < 32; ++t) {
    char* Kc = smem + (t & 1) * 16384;        // current K buffer
    char* Vc = Kc + 8192;                     // current V^T buffer
    char* Kn = smem + ((t & 1) ^ 1) * 16384;  // next K buffer
    char* Vn = Kn + 8192;

    // ---- issue-early: K async -> Kn (drains at end-of-iter barrier); V loads to regs ----
    bf16x8 v0n, v1n;
    const bool pf = (t < 31);
    if (pf) {
      const size_t ktn = (size_t)(t + 1) * 64;
      async16(Kg + ktn * 64, Kn + kldoff);
      async16(Kg + ktn * 64 + 512, Kn + kldoff + 1024);
      v0n = *(const bf16x8*)&Vp[(ktn + k0v) * 64 + c8v * 8];
      v1n = *(const bf16x8*)&Vp[(ktn + k0v + 1) * 64 + c8v * 8];
    }

    // ---- S^T = K Q^T : 8 MFMA (T5) ----
    f32x16 st0 = 0.f, st1 = 0.f;
    __builtin_amdgcn_s_setprio(1);
#pragma unroll
    for (int s = 0; s < 4; ++s) {
      bf16x8 kf = *(const bf16x8*)(Kc + lq * 128 + ((s * 32 + hi * 16) ^ (l7 << 4)));
      st0 = __builtin_amdgcn_mfma_f32_32x32x16_bf16(kf, qf[s], st0, 0, 0, 0);
    }
#pragma unroll
    for (int s = 0; s < 4; ++s) {
      bf16x8 kf = *(const bf16x8*)(Kc + (32 + lq) * 128 + ((s * 32 + hi * 16) ^ (l7 << 4)));
      st1 = __builtin_amdgcn_mfma_f32_32x32x16_bf16(kf, qf[s], st1, 0, 0, 0);
    }
    __builtin_amdgcn_s_setprio(0);

    // ---- online softmax, log2 domain ----
    f32x2 m2 = f32x2{ st0[0], st0[1] };
#pragma unroll
    for (int r = 1; r < 8; ++r) m2 = pkmax(m2, f32x2{ st0[2 * r], st0[2 * r + 1] });
#pragma unroll
    for (int r = 0; r < 8; ++r) m2 = pkmax(m2, f32x2{ st1[2 * r], st1[2 * r + 1] });
    float mx = xmax64(fmaxf(m2.x, m2.y));

    // defer-max (T13): rescale only when max grew past THR=8 (P bounded by 2^8)
    if (!__all(mx - m_run <= 8.f)) {
      const float mnew = fmaxf(m_run, mx);
      const float fs = exp2v(m_run - mnew);
      m_run = mnew;
#pragma unroll
      for (int r = 0; r < 16; ++r) { Oacc0[r] *= fs; Oacc1[r] *= fs; lacc[r] *= fs; }
    }

    // P = exp2(S - m_run)   (sum via l-MFMA below)
    const float mb = m_run;
#pragma unroll
    for (int r = 0; r < 16; ++r) st0[r] = exp2v(st0[r] - mb);
#pragma unroll
    for (int r = 0; r < 16; ++r) st1[r] = exp2v(st1[r] - mb);

    // ---- P -> bf16 B-operand frags in-register (T12) ----
    bf16x8 pa[4];
#pragma unroll
    for (int kb = 0; kb < 2; ++kb) {
      const f32x16& st = kb ? st1 : st0;
#pragma unroll
      for (int s16 = 0; s16 < 2; ++s16) {
        u32 A0 = cvtpk_bf16(st[8 * s16 + 0], st[8 * s16 + 1]);
        u32 B0 = cvtpk_bf16(st[8 * s16 + 4], st[8 * s16 + 5]);
        swap32(A0, B0);
        u32 A1 = cvtpk_bf16(st[8 * s16 + 2], st[8 * s16 + 3]);
        u32 B1 = cvtpk_bf16(st[8 * s16 + 6], st[8 * s16 + 7]);
        swap32(A1, B1);
        union { u32 wv[4]; bf16x8 v; } uu;
        uu.wv[0] = A0; uu.wv[1] = A1; uu.wv[2] = B0; uu.wv[3] = B1;
        pa[kb * 2 + s16] = uu.v;
      }
    }

    // ---- O^T += V^T P^T (8 MFMA) and l += ones . P^T (4 MFMA) (T5) ----
    __builtin_amdgcn_s_setprio(1);
#pragma unroll
    for (int ks = 0; ks < 4; ++ks) {
      bf16x8 vf = *(const bf16x8*)(Vc + lq * 128 + ((ks * 32 + hi * 16) ^ (l7 << 4)));
      Oacc0 = __builtin_amdgcn_mfma_f32_32x32x16_bf16(vf, pa[ks], Oacc0, 0, 0, 0);
      lacc = __builtin_amdgcn_mfma_f32_32x32x16_bf16(onesA, pa[ks], lacc, 0, 0, 0);
    }
#pragma unroll
    for (int ks = 0; ks < 4; ++ks) {
      bf16x8 vf = *(const bf16x8*)(Vc + (32 + lq) * 128 + ((ks * 32 + hi * 16) ^ (l7 << 4)));
      Oacc1 = __builtin_amdgcn_mfma_f32_32x32x16_bf16(vf, pa[ks], Oacc1, 0, 0, 0);
    }
    __builtin_amdgcn_s_setprio(0);

    // ---- write-late: V tile t+1 into the other buffer ----
    if (pf) {
#pragma unroll
      for (int j = 0; j < 8; ++j) {
        const int d = c8v * 8 + j;
        bf16x2 pr = { v0n[j], v1n[j] };
        *(bf16x2*)(Vn + ((d * 128 + k0v * 2) ^ ((d & 7) << 4))) = pr;
      }
    }
    __syncthreads();  // drains vmcnt (K async lands) + lgkm (V writes visible)
  }

  // ---- epilogue: lane (lq,hi) owns q=q0+lq, d = db*32 + rg*8 + hi*4 + 0..3 ----
  const float inv = 1.0f / lacc[0];   // every row of lacc = l(q=lq)
  const int b = bh >> 4, h = bh & 15;
  __bf16* orow = Out + ((size_t)(b * 2048 + q0 + lq)) * 1024 + h * 64;
#pragma unroll
  for (int db = 0; db < 2; ++db) {
    const f32x16& O = db ? Oacc1 : Oacc0;
#pragma unroll
    for (int rg = 0; rg < 4; ++rg) {
      u32 plo = cvtpk_bf16(O[rg * 4 + 0] * inv, O[rg * 4 + 1] * inv);
      u32 phi = cvtpk_bf16(O[rg * 4 + 2] * inv, O[rg * 4 + 3] * inv);
      u32x2 pk = { plo, phi };
      *(u32x2*)&orow[db * 32 + rg * 8 + hi * 4] = pk;
    }
  }
}

// ---------------- launcher ----------------
extern "C" void kernel_launch(void* const* d_in, const int* in_sizes, int n_in,
                              void* d_out, int out_size, void* d_ws, size_t ws_size,
                              hipStream_t stream) {
  const float* x  = (const float*)d_in[0];
  const float* wq = (const float*)d_in[1];
  const float* wp = (const float*)d_in[2];
  const float* bp = (const float*)d_in[3];
  char* ws = (char*)d_ws;

  __bf16* xo   = (__bf16*)(ws);               // 16 MB (reused as attn-out)
  __bf16* wqo  = (__bf16*)(ws + 16777216);
  __bf16* wpo  = (__bf16*)(ws + 23068672);
  __bf16* qkv  = (__bf16*)(ws + 25165824);    // 48 MB [3][64][2048][64]
  __bf16* aout = xo;
  float* y = (float*)d_out;

  cast_to_bf16<<<12288, 256, 0, stream>>>(x, wq, wp, xo, wqo, wpo);
  gemm_bt<0><<<dim3(64, 24), 256, 0, stream>>>(xo, wqo, qkv, nullptr, nullptr);
  mhsa_attn<<<1024, 256, 0, stream>>>(qkv, aout);
  gemm_bt<1><<<dim3(64, 8), 256, 0, stream>>>(aout, wpo, nullptr, y, bp);
}

// Round 14
// 203.469 us; speedup vs baseline: 1.0518x; 1.0518x over previous
//
#include <hip/hip_runtime.h>

// MHSA: B=4, N=2048, C=1024, H=16, HD=64
// cast(f32->bf16) -> GEMM1 (qkv, Q pre-scaled by 0.125*log2e) -> flash attn (swapped 32x32) -> GEMM2 (+bias)
// R14 = R10 exact (best verified: 202.4us). R12's counted-vmcnt ring and R13's XCD swizzle both
// regressed the GEMMs (T4 needs 8-phase interleave; T1 chunked the wrong operand) — reverted.

typedef float f32x2 __attribute__((ext_vector_type(2)));
typedef float f32x4 __attribute__((ext_vector_type(4)));
typedef float f32x16 __attribute__((ext_vector_type(16)));
typedef __bf16 bf16x8 __attribute__((ext_vector_type(8)));
typedef __bf16 bf16x4 __attribute__((ext_vector_type(4)));
typedef __bf16 bf16x2 __attribute__((ext_vector_type(2)));
typedef unsigned int u32;
typedef unsigned int u32x2 __attribute__((ext_vector_type(2)));

__device__ __forceinline__ void async16(const void* g, void* l) {
  __builtin_amdgcn_global_load_lds((const __attribute__((address_space(1))) unsigned int*)g,
                                   (__attribute__((address_space(3))) unsigned int*)l, 16, 0, 0);
}
__device__ __forceinline__ u32 cvtpk_bf16(float lo, float hi) {
  u32 r;
  asm("v_cvt_pk_bf16_f32 %0, %1, %2" : "=v"(r) : "v"(lo), "v"(hi));
  return r;
}
// v_permlane32_swap_b32 a, b : a.row1 <-> b.row0. Only with DISTINCT sources (never self-swap).
__device__ __forceinline__ void swap32(u32& a, u32& b) {
  asm volatile("v_permlane32_swap_b32 %0, %1" : "+v"(a), "+v"(b));
}
__device__ __forceinline__ float xmax64(float x) { return fmaxf(x, __shfl_xor(x, 32, 64)); }
__device__ __forceinline__ float exp2v(float x) { return __builtin_amdgcn_exp2f(x); }
__device__ __forceinline__ f32x2 pkmax(f32x2 a, f32x2 b) {
  return f32x2{ fmaxf(a.x, b.x), fmaxf(a.y, b.y) };
}

// ---------------- cast: x, w_qkv, w_proj f32 -> bf16 ----------------
__global__ __launch_bounds__(256) void cast_to_bf16(const float* __restrict__ x,
                                                    const float* __restrict__ wq,
                                                    const float* __restrict__ wp,
                                                    __bf16* __restrict__ xo,
                                                    __bf16* __restrict__ wqo,
                                                    __bf16* __restrict__ wpo) {
  long i = (long)blockIdx.x * 256 + threadIdx.x;
  const float* s; __bf16* d; long j;
  if (i < 2097152L)      { s = x;  d = xo;  j = i; }
  else if (i < 2883584L) { s = wq; d = wqo; j = i - 2097152L; }
  else                   { s = wp; d = wpo; j = i - 2883584L; }
  float4 v = ((const float4*)s)[j];
  bf16x4 o = { (__bf16)v.x, (__bf16)v.y, (__bf16)v.z, (__bf16)v.w };
  ((bf16x4*)d)[j] = o;
}

// ---------------- GEMM (B^T), m97 structure (verified R1/R3/R10) ----------------
template <int EPI>
__global__ __launch_bounds__(256) void gemm_bt(const __bf16* __restrict__ A,
                                               const __bf16* __restrict__ Bw,
                                               __bf16* __restrict__ Oq,
                                               float* __restrict__ Of,
                                               const float* __restrict__ bias) {
  const int tid = threadIdx.x;
  const int lane = tid & 63, w = tid >> 6;
  const int arow = lane & 15, agrp = lane >> 4;
  const int wm = w >> 1, wn = w & 1;
  const int bm = blockIdx.x, bn = blockIdx.y;
  __shared__ __bf16 As[128 * 32];
  __shared__ __bf16 Bs[128 * 32];
  f32x4 acc[4][4] = {};

  const int c0 = tid, c1 = tid + 256;
  const __bf16* Ag0 = A + ((size_t)(bm * 128 + (c0 >> 2)) << 10) + (c0 & 3) * 8;
  const __bf16* Ag1 = A + ((size_t)(bm * 128 + (c1 >> 2)) << 10) + (c1 & 3) * 8;
  const __bf16* Bg0 = Bw + ((size_t)(bn * 128 + (c0 >> 2)) << 10) + (c0 & 3) * 8;
  const __bf16* Bg1 = Bw + ((size_t)(bn * 128 + (c1 >> 2)) << 10) + (c1 & 3) * 8;

  for (int kt = 0; kt < 1024; kt += 32) {
    async16(Ag0 + kt, &As[c0 * 8]);
    async16(Ag1 + kt, &As[c1 * 8]);
    async16(Bg0 + kt, &Bs[c0 * 8]);
    async16(Bg1 + kt, &Bs[c1 * 8]);
    __syncthreads();
    bf16x8 af[4], bfr[4];
#pragma unroll
    for (int mi = 0; mi < 4; ++mi)
      af[mi] = *(const bf16x8*)&As[(wm * 64 + mi * 16 + arow) * 32 + agrp * 8];
#pragma unroll
    for (int ni = 0; ni < 4; ++ni)
      bfr[ni] = *(const bf16x8*)&Bs[(wn * 64 + ni * 16 + arow) * 32 + agrp * 8];
#pragma unroll
    for (int mi = 0; mi < 4; ++mi)
#pragma unroll
      for (int ni = 0; ni < 4; ++ni)
        acc[mi][ni] = __builtin_amdgcn_mfma_f32_16x16x32_bf16(af[mi], bfr[ni], acc[mi][ni], 0, 0, 0);
    __syncthreads();
  }

  const int rowb = bm * 128 + wm * 64 + agrp * 4;
  const int colb = bn * 128 + wn * 64 + arow;
  if (EPI == 0) {
#pragma unroll
    for (int mi = 0; mi < 4; ++mi) {
      const int row = rowb + mi * 16;
      const int bidx = row >> 11;
#pragma unroll
      for (int ni = 0; ni < 4; ++ni) {
        f32x4 v = acc[mi][ni];
        const int col = colb + ni * 16;
        const int which = col >> 10;
        const int h = (col >> 6) & 15;
        const int hd = col & 63;
        // Q pre-scale: 0.125 * log2(e) so attn softmax runs in exp2 domain
        const float s = (which == 0) ? 0.18033688011112042f : 1.0f;
        __bf16* dst = Oq + ((size_t)which * 64 + bidx * 16 + h) * (size_t)(2048 * 64) + hd;
#pragma unroll
        for (int i = 0; i < 4; ++i)
          dst[(size_t)((row + i) & 2047) * 64] = (__bf16)(v[i] * s);
      }
    }
  } else {
#pragma unroll
    for (int mi = 0; mi < 4; ++mi) {
      const int row = rowb + mi * 16;
#pragma unroll
      for (int ni = 0; ni < 4; ++ni) {
        const int col = colb + ni * 16;
        const float bv = bias[col];
        f32x4 v = acc[mi][ni];
#pragma unroll
        for (int i = 0; i < 4; ++i)
          Of[(size_t)(row + i) * 1024 + col] = v[i] + bv;
      }
    }
  }
}

// ---------------- flash attention (R10, verified: 117.5us) ----------------
// At its structural LDS-port roofline: MfmaUtil 31% == port cap for 20 MFMA : 16 b128-reads/iter.
__global__ __launch_bounds__(256) void mhsa_attn(const __bf16* __restrict__ QKV,
                                                 __bf16* __restrict__ Out) {
  const int tid = threadIdx.x;
  const int lane = tid & 63, w = tid >> 6;
  const int blk = blockIdx.x;           // blk = qt*64 + bh -> XCD(blk%8)=bh%8: KV L2-resident per XCD
  const int bh = blk & 63, qt = blk >> 6;
  const int lq = lane & 31, hi = lane >> 5;
  const int l7 = lane & 7, l3 = lane >> 3;

  const size_t bhoff = (size_t)bh * (2048 * 64);
  const __bf16* Qp = QKV + bhoff;
  const __bf16* Kp = QKV + (size_t)(64 * 2048 * 64) + bhoff;
  const __bf16* Vp = QKV + (size_t)(128 * 2048 * 64) + bhoff;

  __shared__ char smem[32768];  // 2 x {K [64][64] swz (8KB) | V^T [64][64] swz (8KB)}

  const int q0 = qt * 128 + w * 32;

  bf16x8 qf[4];
#pragma unroll
  for (int s = 0; s < 4; ++s)
    qf[s] = *(const bf16x8*)&Qp[(size_t)(q0 + lq) * 64 + s * 16 + hi * 8];

  // all-ones bf16 A-operand for the l-MFMA (layout-invariant)
  union { u32 wv[4]; bf16x8 v; } ou;
  ou.wv[0] = ou.wv[1] = ou.wv[2] = ou.wv[3] = 0x3F803F80u;
  const bf16x8 onesA = ou.v;

  f32x16 Oacc0 = 0.f, Oacc1 = 0.f;   // OT: col=lane&31=q, d(per 32-blk)=(r&3)+8*(r>>2)+4*hi
  f32x16 lacc = 0.f;                 // l accumulator: every row = sum_k P[k][q=lq]
  float m_run = -1e30f;

  const __bf16* Kg = Kp + (size_t)(w * 16 + l3) * 64 + ((l7 ^ l3) * 8);
  const int kldoff = w * 2048 + lane * 16;

  const int c8v = tid >> 5, k0v = (tid & 31) * 2;

  // ---- prologue: stage tile 0 into buf0 ----
  {
    async16(Kg, smem + kldoff);
    async16(Kg + 512, smem + kldoff + 1024);
    bf16x8 v0 = *(const bf16x8*)&Vp[(size_t)k0v * 64 + c8v * 8];
    bf16x8 v1 = *(const bf16x8*)&Vp[(size_t)(k0v + 1) * 64 + c8v * 8];
    char* Vb = smem + 8192;
#pragma unroll
    for (int j = 0; j < 8; ++j) {
      const int d = c8v * 8 + j;
      bf16x2 pr = { v0[j], v1[j] };
      *(bf16x2*)(Vb + ((d * 128 + k0v * 2) ^ ((d & 7) << 4))) = pr;
    }
  }
  __syncthreads();  // drains vmcnt -> K tile0 resident

  for (int t = 0; t < 32; ++t) {
    char* Kc = smem + (t & 1) * 16384;        // current K buffer
    char* Vc = Kc + 8192;                     // current V^T buffer
    char* Kn = smem + ((t & 1) ^ 1) * 16384;  // next K buffer
    char* Vn = Kn + 8192;

    // ---- issue-early: K async -> Kn (drains at end-of-iter barrier); V loads to regs ----
    bf16x8 v0n, v1n;
    const bool pf = (t < 31);
    if (pf) {
      const size_t ktn = (size_t)(t + 1) * 64;
      async16(Kg + ktn * 64, Kn + kldoff);
      async16(Kg + ktn * 64 + 512, Kn + kldoff + 1024);
      v0n = *(const bf16x8*)&Vp[(ktn + k0v) * 64 + c8v * 8];
      v1n = *(const bf16x8*)&Vp[(ktn + k0v + 1) * 64 + c8v * 8];
    }

    // ---- S^T = K Q^T : 8 MFMA (T5) ----
    f32x16 st0 = 0.f, st1 = 0.f;
    __builtin_amdgcn_s_setprio(1);
#pragma unroll
    for (int s = 0; s < 4; ++s) {
      bf16x8 kf = *(const bf16x8*)(Kc + lq * 128 + ((s * 32 + hi * 16) ^ (l7 << 4)));
      st0 = __builtin_amdgcn_mfma_f32_32x32x16_bf16(kf, qf[s], st0, 0, 0, 0);
    }
#pragma unroll
    for (int s = 0; s < 4; ++s) {
      bf16x8 kf = *(const bf16x8*)(Kc + (32 + lq) * 128 + ((s * 32 + hi * 16) ^ (l7 << 4)));
      st1 = __builtin_amdgcn_mfma_f32_32x32x16_bf16(kf, qf[s], st1, 0, 0, 0);
    }
    __builtin_amdgcn_s_setprio(0);

    // ---- online softmax, log2 domain ----
    f32x2 m2 = f32x2{ st0[0], st0[1] };
#pragma unroll
    for (int r = 1; r < 8; ++r) m2 = pkmax(m2, f32x2{ st0[2 * r], st0[2 * r + 1] });
#pragma unroll
    for (int r = 0; r < 8; ++r) m2 = pkmax(m2, f32x2{ st1[2 * r], st1[2 * r + 1] });
    float mx = xmax64(fmaxf(m2.x, m2.y));

    // defer-max (T13): rescale only when max grew past THR=8 (P bounded by 2^8)
    if (!__all(mx - m_run <= 8.f)) {
      const float mnew = fmaxf(m_run, mx);
      const float fs = exp2v(m_run - mnew);
      m_run = mnew;
#pragma unroll
      for (int r = 0; r < 16; ++r) { Oacc0[r] *= fs; Oacc1[r] *= fs; lacc[r] *= fs; }
    }

    // P = exp2(S - m_run)   (sum via l-MFMA below)
    const float mb = m_run;
#pragma unroll
    for (int r = 0; r < 16; ++r) st0[r] = exp2v(st0[r] - mb);
#pragma unroll
    for (int r = 0; r < 16; ++r) st1[r] = exp2v(st1[r] - mb);

    // ---- P -> bf16 B-operand frags in-register (T12) ----
    bf16x8 pa[4];
#pragma unroll
    for (int kb = 0; kb < 2; ++kb) {
      const f32x16& st = kb ? st1 : st0;
#pragma unroll
      for (int s16 = 0; s16 < 2; ++s16) {
        u32 A0 = cvtpk_bf16(st[8 * s16 + 0], st[8 * s16 + 1]);
        u32 B0 = cvtpk_bf16(st[8 * s16 + 4], st[8 * s16 + 5]);
        swap32(A0, B0);
        u32 A1 = cvtpk_bf16(st[8 * s16 + 2], st[8 * s16 + 3]);
        u32 B1 = cvtpk_bf16(st[8 * s16 + 6], st[8 * s16 + 7]);
        swap32(A1, B1);
        union { u32 wv[4]; bf16x8 v; } uu;
        uu.wv[0] = A0; uu.wv[1] = A1; uu.wv[2] = B0; uu.wv[3] = B1;
        pa[kb * 2 + s16] = uu.v;
      }
    }

    // ---- O^T += V^T P^T (8 MFMA) and l += ones . P^T (4 MFMA) (T5) ----
    __builtin_amdgcn_s_setprio(1);
#pragma unroll
    for (int ks = 0; ks < 4; ++ks) {
      bf16x8 vf = *(const bf16x8*)(Vc + lq * 128 + ((ks * 32 + hi * 16) ^ (l7 << 4)));
      Oacc0 = __builtin_amdgcn_mfma_f32_32x32x16_bf16(vf, pa[ks], Oacc0, 0, 0, 0);
      lacc = __builtin_amdgcn_mfma_f32_32x32x16_bf16(onesA, pa[ks], lacc, 0, 0, 0);
    }
#pragma unroll
    for (int ks = 0; ks < 4; ++ks) {
      bf16x8 vf = *(const bf16x8*)(Vc + (32 + lq) * 128 + ((ks * 32 + hi * 16) ^ (l7 << 4)));
      Oacc1 = __builtin_amdgcn_mfma_f32_32x32x16_bf16(vf, pa[ks], Oacc1, 0, 0, 0);
    }
    __builtin_amdgcn_s_setprio(0);

    // ---- write-late: V tile t+1 into the other buffer ----
    if (pf) {
#pragma unroll
      for (int j = 0; j < 8; ++j) {
        const int d = c8v * 8 + j;
        bf16x2 pr = { v0n[j], v1n[j] };
        *(bf16x2*)(Vn + ((d * 128 + k0v * 2) ^ ((d & 7) << 4))) = pr;
      }
    }
    __syncthreads();  // drains vmcnt (K async lands) + lgkm (V writes visible)
  }

  // ---- epilogue: lane (lq,hi) owns q=q0+lq, d = db*32 + rg*8 + hi*4 + 0..3 ----
  const float inv = 1.0f / lacc[0];   // every row of lacc = l(q=lq)
  const int b = bh >> 4, h = bh & 15;
  __bf16* orow = Out + ((size_t)(b * 2048 + q0 + lq)) * 1024 + h * 64;
#pragma unroll
  for (int db = 0; db < 2; ++db) {
    const f32x16& O = db ? Oacc1 : Oacc0;
#pragma unroll
    for (int rg = 0; rg < 4; ++rg) {
      u32 plo = cvtpk_bf16(O[rg * 4 + 0] * inv, O[rg * 4 + 1] * inv);
      u32 phi = cvtpk_bf16(O[rg * 4 + 2] * inv, O[rg * 4 + 3] * inv);
      u32x2 pk = { plo, phi };
      *(u32x2*)&orow[db * 32 + rg * 8 + hi * 4] = pk;
    }
  }
}

// ---------------- launcher ----------------
extern "C" void kernel_launch(void* const* d_in, const int* in_sizes, int n_in,
                              void* d_out, int out_size, void* d_ws, size_t ws_size,
                              hipStream_t stream) {
  const float* x  = (const float*)d_in[0];
  const float* wq = (const float*)d_in[1];
  const float* wp = (const float*)d_in[2];
  const float* bp = (const float*)d_in[3];
  char* ws = (char*)d_ws;

  __bf16* xo   = (__bf16*)(ws);               // 16 MB (reused as attn-out)
  __bf16* wqo  = (__bf16*)(ws + 16777216);
  __bf16* wpo  = (__bf16*)(ws + 23068672);
  __bf16* qkv  = (__bf16*)(ws + 25165824);    // 48 MB [3][64][2048][64]
  __bf16* aout = xo;
  float* y = (float*)d_out;

  cast_to_bf16<<<12288, 256, 0, stream>>>(x, wq, wp, xo, wqo, wpo);
  gemm_bt<0><<<dim3(64, 24), 256, 0, stream>>>(xo, wqo, qkv, nullptr, nullptr);
  mhsa_attn<<<1024, 256, 0, stream>>>(qkv, aout);
  gemm_bt<1><<<dim3(64, 8), 256, 0, stream>>>(aout, wpo, nullptr, y, bp);
}

// Round 16
// 192.903 us; speedup vs baseline: 1.1094x; 1.0548x over previous
//
#include <hip/hip_runtime.h>

// MHSA: B=4, N=2048, C=1024, H=16, HD=64
// cast(f32->bf16) -> GEMM1 (qkv, Q pre-scaled by 0.125*log2e) -> flash attn (swapped 32x32) -> GEMM2 (+bias)
// R15 = R10 + GEMM BK=64 (half the barriers/drains) with the R9-verified swizzle composition:
//   global_load_lds linear dest + inverse-swizzled global source (col chunk ^= row&7) +
//   read-side XOR ((row&7)<<4). 128B-row-stride b128 reads are 2-way aliased (free) not 32-way.

typedef float f32x2 __attribute__((ext_vector_type(2)));
typedef float f32x4 __attribute__((ext_vector_type(4)));
typedef float f32x16 __attribute__((ext_vector_type(16)));
typedef __bf16 bf16x8 __attribute__((ext_vector_type(8)));
typedef __bf16 bf16x4 __attribute__((ext_vector_type(4)));
typedef __bf16 bf16x2 __attribute__((ext_vector_type(2)));
typedef unsigned int u32;
typedef unsigned int u32x2 __attribute__((ext_vector_type(2)));

__device__ __forceinline__ void async16(const void* g, void* l) {
  __builtin_amdgcn_global_load_lds((const __attribute__((address_space(1))) unsigned int*)g,
                                   (__attribute__((address_space(3))) unsigned int*)l, 16, 0, 0);
}
__device__ __forceinline__ u32 cvtpk_bf16(float lo, float hi) {
  u32 r;
  asm("v_cvt_pk_bf16_f32 %0, %1, %2" : "=v"(r) : "v"(lo), "v"(hi));
  return r;
}
// v_permlane32_swap_b32 a, b : a.row1 <-> b.row0. Only with DISTINCT sources (never self-swap).
__device__ __forceinline__ void swap32(u32& a, u32& b) {
  asm volatile("v_permlane32_swap_b32 %0, %1" : "+v"(a), "+v"(b));
}
__device__ __forceinline__ float xmax64(float x) { return fmaxf(x, __shfl_xor(x, 32, 64)); }
__device__ __forceinline__ float exp2v(float x) { return __builtin_amdgcn_exp2f(x); }
__device__ __forceinline__ f32x2 pkmax(f32x2 a, f32x2 b) {
  return f32x2{ fmaxf(a.x, b.x), fmaxf(a.y, b.y) };
}

// ---------------- cast: x, w_qkv, w_proj f32 -> bf16 ----------------
__global__ __launch_bounds__(256) void cast_to_bf16(const float* __restrict__ x,
                                                    const float* __restrict__ wq,
                                                    const float* __restrict__ wp,
                                                    __bf16* __restrict__ xo,
                                                    __bf16* __restrict__ wqo,
                                                    __bf16* __restrict__ wpo) {
  long i = (long)blockIdx.x * 256 + threadIdx.x;
  const float* s; __bf16* d; long j;
  if (i < 2097152L)      { s = x;  d = xo;  j = i; }
  else if (i < 2883584L) { s = wq; d = wqo; j = i - 2097152L; }
  else                   { s = wp; d = wpo; j = i - 2883584L; }
  float4 v = ((const float4*)s)[j];
  bf16x4 o = { (__bf16)v.x, (__bf16)v.y, (__bf16)v.z, (__bf16)v.w };
  ((bf16x4*)d)[j] = o;
}

// ---------------- GEMM (B^T): m97 wave structure, BK=64, swizzled LDS ----------------
// 128x128 tile, 4 waves (2x2), 4x4 frags of 16x16x32 MFMA. 16 K-iters (was 32) -> half the
// vmcnt(0)+barrier drains. LDS 2x16KB. Chunk c(0..1023): row=c>>3, cc=c&7; source col chunk
// sc = cc ^ (row&7); LDS dest linear c*16. Read: row*128 + ((kk*64+agrp*16) ^ ((arow&7)<<4)).
template <int EPI>
__global__ __launch_bounds__(256) void gemm_bt(const __bf16* __restrict__ A,
                                               const __bf16* __restrict__ Bw,
                                               __bf16* __restrict__ Oq,
                                               float* __restrict__ Of,
                                               const float* __restrict__ bias) {
  const int tid = threadIdx.x;
  const int lane = tid & 63, w = tid >> 6;
  const int arow = lane & 15, agrp = lane >> 4;
  const int wm = w >> 1, wn = w & 1;
  const int bm = blockIdx.x, bn = blockIdx.y;
  __shared__ char gsm[32768];   // As 16KB | Bs 16KB
  char* AsB = gsm;
  char* BsB = gsm + 16384;
  f32x4 acc[4][4] = {};

  // staging geometry: thread covers chunks c = tid + 256k, k=0..3; row = c>>3 (row&7 const in k)
  const int row0 = tid >> 3, cc0 = tid & 7;
  const int sc0 = cc0 ^ (row0 & 7);
  const __bf16* Ag = A + ((size_t)(bm * 128 + row0) << 10) + sc0 * 8;
  const __bf16* Bg = Bw + ((size_t)(bn * 128 + row0) << 10) + sc0 * 8;
  const int ld0 = tid * 16;  // + k*4096 ; per-wave: uniform base + lane*16 ✓

  for (int kt = 0; kt < 1024; kt += 64) {
#pragma unroll
    for (int k = 0; k < 4; ++k) {
      async16(Ag + kt + (size_t)k * 32768, AsB + ld0 + k * 4096);
      async16(Bg + kt + (size_t)k * 32768, BsB + ld0 + k * 4096);
    }
    __syncthreads();
#pragma unroll
    for (int kk = 0; kk < 2; ++kk) {
      bf16x8 af[4], bfr[4];
      const int csw = (kk * 64 + agrp * 16) ^ ((arow & 7) << 4);
#pragma unroll
      for (int mi = 0; mi < 4; ++mi)
        af[mi] = *(const bf16x8*)(AsB + (wm * 64 + mi * 16 + arow) * 128 + csw);
#pragma unroll
      for (int ni = 0; ni < 4; ++ni)
        bfr[ni] = *(const bf16x8*)(BsB + (wn * 64 + ni * 16 + arow) * 128 + csw);
      __builtin_amdgcn_s_setprio(1);
#pragma unroll
      for (int mi = 0; mi < 4; ++mi)
#pragma unroll
        for (int ni = 0; ni < 4; ++ni)
          acc[mi][ni] = __builtin_amdgcn_mfma_f32_16x16x32_bf16(af[mi], bfr[ni], acc[mi][ni], 0, 0, 0);
      __builtin_amdgcn_s_setprio(0);
    }
    __syncthreads();
  }

  const int rowb = bm * 128 + wm * 64 + agrp * 4;
  const int colb = bn * 128 + wn * 64 + arow;
  if (EPI == 0) {
#pragma unroll
    for (int mi = 0; mi < 4; ++mi) {
      const int row = rowb + mi * 16;
      const int bidx = row >> 11;
#pragma unroll
      for (int ni = 0; ni < 4; ++ni) {
        f32x4 v = acc[mi][ni];
        const int col = colb + ni * 16;
        const int which = col >> 10;
        const int h = (col >> 6) & 15;
        const int hd = col & 63;
        // Q pre-scale: 0.125 * log2(e) so attn softmax runs in exp2 domain
        const float s = (which == 0) ? 0.18033688011112042f : 1.0f;
        __bf16* dst = Oq + ((size_t)which * 64 + bidx * 16 + h) * (size_t)(2048 * 64) + hd;
#pragma unroll
        for (int i = 0; i < 4; ++i)
          dst[(size_t)((row + i) & 2047) * 64] = (__bf16)(v[i] * s);
      }
    }
  } else {
#pragma unroll
    for (int mi = 0; mi < 4; ++mi) {
      const int row = rowb + mi * 16;
#pragma unroll
      for (int ni = 0; ni < 4; ++ni) {
        const int col = colb + ni * 16;
        const float bv = bias[col];
        f32x4 v = acc[mi][ni];
#pragma unroll
        for (int i = 0; i < 4; ++i)
          Of[(size_t)(row + i) * 1024 + col] = v[i] + bv;
      }
    }
  }
}

// ---------------- flash attention (R10, verified: 117.5us) ----------------
// At its structural LDS-port roofline: MfmaUtil 31% == port cap for 20 MFMA : 16 b128-reads/iter.
__global__ __launch_bounds__(256) void mhsa_attn(const __bf16* __restrict__ QKV,
                                                 __bf16* __restrict__ Out) {
  const int tid = threadIdx.x;
  const int lane = tid & 63, w = tid >> 6;
  const int blk = blockIdx.x;           // blk = qt*64 + bh -> XCD(blk%8)=bh%8: KV L2-resident per XCD
  const int bh = blk & 63, qt = blk >> 6;
  const int lq = lane & 31, hi = lane >> 5;
  const int l7 = lane & 7, l3 = lane >> 3;

  const size_t bhoff = (size_t)bh * (2048 * 64);
  const __bf16* Qp = QKV + bhoff;
  const __bf16* Kp = QKV + (size_t)(64 * 2048 * 64) + bhoff;
  const __bf16* Vp = QKV + (size_t)(128 * 2048 * 64) + bhoff;

  __shared__ char smem[32768];  // 2 x {K [64][64] swz (8KB) | V^T [64][64] swz (8KB)}

  const int q0 = qt * 128 + w * 32;

  bf16x8 qf[4];
#pragma unroll
  for (int s = 0; s < 4; ++s)
    qf[s] = *(const bf16x8*)&Qp[(size_t)(q0 + lq) * 64 + s * 16 + hi * 8];

  // all-ones bf16 A-operand for the l-MFMA (layout-invariant)
  union { u32 wv[4]; bf16x8 v; } ou;
  ou.wv[0] = ou.wv[1] = ou.wv[2] = ou.wv[3] = 0x3F803F80u;
  const bf16x8 onesA = ou.v;

  f32x16 Oacc0 = 0.f, Oacc1 = 0.f;   // OT: col=lane&31=q, d(per 32-blk)=(r&3)+8*(r>>2)+4*hi
  f32x16 lacc = 0.f;                 // l accumulator: every row = sum_k P[k][q=lq]
  float m_run = -1e30f;

  const __bf16* Kg = Kp + (size_t)(w * 16 + l3) * 64 + ((l7 ^ l3) * 8);
  const int kldoff = w * 2048 + lane * 16;

  const int c8v = tid >> 5, k0v = (tid & 31) * 2;

  // ---- prologue: stage tile 0 into buf0 ----
  {
    async16(Kg, smem + kldoff);
    async16(Kg + 512, smem + kldoff + 1024);
    bf16x8 v0 = *(const bf16x8*)&Vp[(size_t)k0v * 64 + c8v * 8];
    bf16x8 v1 = *(const bf16x8*)&Vp[(size_t)(k0v + 1) * 64 + c8v * 8];
    char* Vb = smem + 8192;
#pragma unroll
    for (int j = 0; j < 8; ++j) {
      const int d = c8v * 8 + j;
      bf16x2 pr = { v0[j], v1[j] };
      *(bf16x2*)(Vb + ((d * 128 + k0v * 2) ^ ((d & 7) << 4))) = pr;
    }
  }
  __syncthreads();  // drains vmcnt -> K tile0 resident

  for (int t = 0; t < 32; ++t) {
    char* Kc = smem + (t & 1) * 16384;        // current K buffer
    char* Vc = Kc + 8192;                     // current V^T buffer
    char* Kn = smem + ((t & 1) ^ 1) * 16384;  // next K buffer
    char* Vn = Kn + 8192;

    // ---- issue-early: K async -> Kn (drains at end-of-iter barrier); V loads to regs ----
    bf16x8 v0n, v1n;
    const bool pf = (t < 31);
    if (pf) {
      const size_t ktn = (size_t)(t + 1) * 64;
      async16(Kg + ktn * 64, Kn + kldoff);
      async16(Kg + ktn * 64 + 512, Kn + kldoff + 1024);
      v0n = *(const bf16x8*)&Vp[(ktn + k0v) * 64 + c8v * 8];
      v1n = *(const bf16x8*)&Vp[(ktn + k0v + 1) * 64 + c8v * 8];
    }

    // ---- S^T = K Q^T : 8 MFMA (T5) ----
    f32x16 st0 = 0.f, st1 = 0.f;
    __builtin_amdgcn_s_setprio(1);
#pragma unroll
    for (int s = 0; s < 4; ++s) {
      bf16x8 kf = *(const bf16x8*)(Kc + lq * 128 + ((s * 32 + hi * 16) ^ (l7 << 4)));
      st0 = __builtin_amdgcn_mfma_f32_32x32x16_bf16(kf, qf[s], st0, 0, 0, 0);
    }
#pragma unroll
    for (int s = 0; s < 4; ++s) {
      bf16x8 kf = *(const bf16x8*)(Kc + (32 + lq) * 128 + ((s * 32 + hi * 16) ^ (l7 << 4)));
      st1 = __builtin_amdgcn_mfma_f32_32x32x16_bf16(kf, qf[s], st1, 0, 0, 0);
    }
    __builtin_amdgcn_s_setprio(0);

    // ---- online softmax, log2 domain ----
    f32x2 m2 = f32x2{ st0[0], st0[1] };
#pragma unroll
    for (int r = 1; r < 8; ++r) m2 = pkmax(m2, f32x2{ st0[2 * r], st0[2 * r + 1] });
#pragma unroll
    for (int r = 0; r < 8; ++r) m2 = pkmax(m2, f32x2{ st1[2 * r], st1[2 * r + 1] });
    float mx = xmax64(fmaxf(m2.x, m2.y));

    // defer-max (T13): rescale only when max grew past THR=8 (P bounded by 2^8)
    if (!__all(mx - m_run <= 8.f)) {
      const float mnew = fmaxf(m_run, mx);
      const float fs = exp2v(m_run - mnew);
      m_run = mnew;
#pragma unroll
      for (int r = 0; r < 16; ++r) { Oacc0[r] *= fs; Oacc1[r] *= fs; lacc[r] *= fs; }
    }

    // P = exp2(S - m_run)   (sum via l-MFMA below)
    const float mb = m_run;
#pragma unroll
    for (int r = 0; r < 16; ++r) st0[r] = exp2v(st0[r] - mb);
#pragma unroll
    for (int r = 0; r < 16; ++r) st1[r] = exp2v(st1[r] - mb);

    // ---- P -> bf16 B-operand frags in-register (T12) ----
    bf16x8 pa[4];
#pragma unroll
    for (int kb = 0; kb < 2; ++kb) {
      const f32x16& st = kb ? st1 : st0;
#pragma unroll
      for (int s16 = 0; s16 < 2; ++s16) {
        u32 A0 = cvtpk_bf16(st[8 * s16 + 0], st[8 * s16 + 1]);
        u32 B0 = cvtpk_bf16(st[8 * s16 + 4], st[8 * s16 + 5]);
        swap32(A0, B0);
        u32 A1 = cvtpk_bf16(st[8 * s16 + 2], st[8 * s16 + 3]);
        u32 B1 = cvtpk_bf16(st[8 * s16 + 6], st[8 * s16 + 7]);
        swap32(A1, B1);
        union { u32 wv[4]; bf16x8 v; } uu;
        uu.wv[0] = A0; uu.wv[1] = A1; uu.wv[2] = B0; uu.wv[3] = B1;
        pa[kb * 2 + s16] = uu.v;
      }
    }

    // ---- O^T += V^T P^T (8 MFMA) and l += ones . P^T (4 MFMA) (T5) ----
    __builtin_amdgcn_s_setprio(1);
#pragma unroll
    for (int ks = 0; ks < 4; ++ks) {
      bf16x8 vf = *(const bf16x8*)(Vc + lq * 128 + ((ks * 32 + hi * 16) ^ (l7 << 4)));
      Oacc0 = __builtin_amdgcn_mfma_f32_32x32x16_bf16(vf, pa[ks], Oacc0, 0, 0, 0);
      lacc = __builtin_amdgcn_mfma_f32_32x32x16_bf16(onesA, pa[ks], lacc, 0, 0, 0);
    }
#pragma unroll
    for (int ks = 0; ks < 4; ++ks) {
      bf16x8 vf = *(const bf16x8*)(Vc + (32 + lq) * 128 + ((ks * 32 + hi * 16) ^ (l7 << 4)));
      Oacc1 = __builtin_amdgcn_mfma_f32_32x32x16_bf16(vf, pa[ks], Oacc1, 0, 0, 0);
    }
    __builtin_amdgcn_s_setprio(0);

    // ---- write-late: V tile t+1 into the other buffer ----
    if (pf) {
#pragma unroll
      for (int j = 0; j < 8; ++j) {
        const int d = c8v * 8 + j;
        bf16x2 pr = { v0n[j], v1n[j] };
        *(bf16x2*)(Vn + ((d * 128 + k0v * 2) ^ ((d & 7) << 4))) = pr;
      }
    }
    __syncthreads();  // drains vmcnt (K async lands) + lgkm (V writes visible)
  }

  // ---- epilogue: lane (lq,hi) owns q=q0+lq, d = db*32 + rg*8 + hi*4 + 0..3 ----
  const float inv = 1.0f / lacc[0];   // every row of lacc = l(q=lq)
  const int b = bh >> 4, h = bh & 15;
  __bf16* orow = Out + ((size_t)(b * 2048 + q0 + lq)) * 1024 + h * 64;
#pragma unroll
  for (int db = 0; db < 2; ++db) {
    const f32x16& O = db ? Oacc1 : Oacc0;
#pragma unroll
    for (int rg = 0; rg < 4; ++rg) {
      u32 plo = cvtpk_bf16(O[rg * 4 + 0] * inv, O[rg * 4 + 1] * inv);
      u32 phi = cvtpk_bf16(O[rg * 4 + 2] * inv, O[rg * 4 + 3] * inv);
      u32x2 pk = { plo, phi };
      *(u32x2*)&orow[db * 32 + rg * 8 + hi * 4] = pk;
    }
  }
}

// ---------------- launcher ----------------
extern "C" void kernel_launch(void* const* d_in, const int* in_sizes, int n_in,
                              void* d_out, int out_size, void* d_ws, size_t ws_size,
                              hipStream_t stream) {
  const float* x  = (const float*)d_in[0];
  const float* wq = (const float*)d_in[1];
  const float* wp = (const float*)d_in[2];
  const float* bp = (const float*)d_in[3];
  char* ws = (char*)d_ws;

  __bf16* xo   = (__bf16*)(ws);               // 16 MB (reused as attn-out)
  __bf16* wqo  = (__bf16*)(ws + 16777216);
  __bf16* wpo  = (__bf16*)(ws + 23068672);
  __bf16* qkv  = (__bf16*)(ws + 25165824);    // 48 MB [3][64][2048][64]
  __bf16* aout = xo;
  float* y = (float*)d_out;

  cast_to_bf16<<<12288, 256, 0, stream>>>(x, wq, wp, xo, wqo, wpo);
  gemm_bt<0><<<dim3(64, 24), 256, 0, stream>>>(xo, wqo, qkv, nullptr, nullptr);
  mhsa_attn<<<1024, 256, 0, stream>>>(qkv, aout);
  gemm_bt<1><<<dim3(64, 8), 256, 0, stream>>>(aout, wpo, nullptr, y, bp);
}

// Round 18
// 187.628 us; speedup vs baseline: 1.1406x; 1.0281x over previous
//
#include <hip/hip_runtime.h>

// MHSA: B=4, N=2048, C=1024, H=16, HD=64
// cast(f32->bf16) -> GEMM1 (qkv, Q pre-scaled by 0.125*log2e) -> flash attn (swapped 32x32) -> GEMM2 (+bias)
// R17 = R16 + GEMM rebuilt as 8-wave (512thr) 128x128 tile, BK=64, TRUE double-buffer:
//   stage(t+1 -> other buf) issued BEFORE compute(t), ONE barrier/iter (16 total, was 32).
//   LDS 64KB -> 2 blocks/CU x 8 waves = 16 waves/CU (vs 12). Swizzle identical to R16-verified.

typedef float f32x2 __attribute__((ext_vector_type(2)));
typedef float f32x4 __attribute__((ext_vector_type(4)));
typedef float f32x16 __attribute__((ext_vector_type(16)));
typedef __bf16 bf16x8 __attribute__((ext_vector_type(8)));
typedef __bf16 bf16x4 __attribute__((ext_vector_type(4)));
typedef __bf16 bf16x2 __attribute__((ext_vector_type(2)));
typedef unsigned int u32;
typedef unsigned int u32x2 __attribute__((ext_vector_type(2)));

__device__ __forceinline__ void async16(const void* g, void* l) {
  __builtin_amdgcn_global_load_lds((const __attribute__((address_space(1))) unsigned int*)g,
                                   (__attribute__((address_space(3))) unsigned int*)l, 16, 0, 0);
}
__device__ __forceinline__ u32 cvtpk_bf16(float lo, float hi) {
  u32 r;
  asm("v_cvt_pk_bf16_f32 %0, %1, %2" : "=v"(r) : "v"(lo), "v"(hi));
  return r;
}
// v_permlane32_swap_b32 a, b : a.row1 <-> b.row0. Only with DISTINCT sources (never self-swap).
__device__ __forceinline__ void swap32(u32& a, u32& b) {
  asm volatile("v_permlane32_swap_b32 %0, %1" : "+v"(a), "+v"(b));
}
__device__ __forceinline__ float xmax64(float x) { return fmaxf(x, __shfl_xor(x, 32, 64)); }
__device__ __forceinline__ float exp2v(float x) { return __builtin_amdgcn_exp2f(x); }
__device__ __forceinline__ f32x2 pkmax(f32x2 a, f32x2 b) {
  return f32x2{ fmaxf(a.x, b.x), fmaxf(a.y, b.y) };
}

// ---------------- cast: x, w_qkv, w_proj f32 -> bf16 ----------------
__global__ __launch_bounds__(256) void cast_to_bf16(const float* __restrict__ x,
                                                    const float* __restrict__ wq,
                                                    const float* __restrict__ wp,
                                                    __bf16* __restrict__ xo,
                                                    __bf16* __restrict__ wqo,
                                                    __bf16* __restrict__ wpo) {
  long i = (long)blockIdx.x * 256 + threadIdx.x;
  const float* s; __bf16* d; long j;
  if (i < 2097152L)      { s = x;  d = xo;  j = i; }
  else if (i < 2883584L) { s = wq; d = wqo; j = i - 2097152L; }
  else                   { s = wp; d = wpo; j = i - 2883584L; }
  float4 v = ((const float4*)s)[j];
  bf16x4 o = { (__bf16)v.x, (__bf16)v.y, (__bf16)v.z, (__bf16)v.w };
  ((bf16x4*)d)[j] = o;
}

// ---------------- GEMM (B^T): 8-wave 128x128, BK=64, double-buffered (R17) ----------------
// Waves 2x4 (wm 0..1, wn 0..3); wave tile 64x32 = 4x2 frags of 16x16x32 MFMA.
// LDS: 2 buffers x {A 16KB | B 16KB}. Stage: chunk c -> row=c>>3, cc=c&7, src col-chunk
// cc^(row&7), dest linear c*16 (uniform base + lane*16 per wave). Read: row*128 +
// ((kk*64+agrp*16) ^ ((arow&7)<<4)) — R16-verified swizzle composition, 2-way conflicts.
template <int EPI>
__global__ __launch_bounds__(512) void gemm_bt(const __bf16* __restrict__ A,
                                               const __bf16* __restrict__ Bw,
                                               __bf16* __restrict__ Oq,
                                               float* __restrict__ Of,
                                               const float* __restrict__ bias) {
  const int tid = threadIdx.x;
  const int lane = tid & 63, w = tid >> 6;
  const int arow = lane & 15, agrp = lane >> 4;
  const int wm = w >> 2, wn = w & 3;
  const int bm = blockIdx.x, bn = blockIdx.y;
  __shared__ char gsm[65536];   // 2 x {A 16KB | B 16KB}
  f32x4 acc[4][2] = {};

  // staging: thread covers chunks c0=tid (rows 0..63), c1=tid+512 (rows 64..127); row&7 equal.
  const int row0 = tid >> 3, cc0 = tid & 7;
  const int sc0 = cc0 ^ (row0 & 7);
  const __bf16* Ag0 = A + ((size_t)(bm * 128 + row0) << 10) + sc0 * 8;
  const __bf16* Ag1 = A + ((size_t)(bm * 128 + row0 + 64) << 10) + sc0 * 8;
  const __bf16* Bg0 = Bw + ((size_t)(bn * 128 + row0) << 10) + sc0 * 8;
  const __bf16* Bg1 = Bw + ((size_t)(bn * 128 + row0 + 64) << 10) + sc0 * 8;
  const int ld0 = tid * 16;

#define GSTAGE(buf, kt)                                   \
  {                                                       \
    char* S_ = gsm + (buf) * 32768;                       \
    async16(Ag0 + (kt), S_ + ld0);                        \
    async16(Ag1 + (kt), S_ + 8192 + ld0);                 \
    async16(Bg0 + (kt), S_ + 16384 + ld0);                \
    async16(Bg1 + (kt), S_ + 24576 + ld0);                \
  }

  GSTAGE(0, 0)
  __syncthreads();  // drains vmcnt: tile 0 resident

  for (int t = 0; t < 16; ++t) {
    if (t < 15) GSTAGE((t + 1) & 1, (t + 1) * 64)   // issue-early into other buffer
    char* AsB = gsm + (t & 1) * 32768;
    char* BsB = AsB + 16384;
#pragma unroll
    for (int kk = 0; kk < 2; ++kk) {
      bf16x8 af[4], bfr[2];
      const int csw = (kk * 64 + agrp * 16) ^ ((arow & 7) << 4);
#pragma unroll
      for (int mi = 0; mi < 4; ++mi)
        af[mi] = *(const bf16x8*)(AsB + (wm * 64 + mi * 16 + arow) * 128 + csw);
#pragma unroll
      for (int ni = 0; ni < 2; ++ni)
        bfr[ni] = *(const bf16x8*)(BsB + (wn * 32 + ni * 16 + arow) * 128 + csw);
      __builtin_amdgcn_s_setprio(1);
#pragma unroll
      for (int mi = 0; mi < 4; ++mi)
#pragma unroll
        for (int ni = 0; ni < 2; ++ni)
          acc[mi][ni] = __builtin_amdgcn_mfma_f32_16x16x32_bf16(af[mi], bfr[ni], acc[mi][ni], 0, 0, 0);
      __builtin_amdgcn_s_setprio(0);
    }
    __syncthreads();  // drains vmcnt (stage t+1 landed) + guards buffer reuse
  }
#undef GSTAGE

  const int rowb = bm * 128 + wm * 64 + agrp * 4;
  const int colb = bn * 128 + wn * 32 + arow;
  if (EPI == 0) {
#pragma unroll
    for (int mi = 0; mi < 4; ++mi) {
      const int row = rowb + mi * 16;
      const int bidx = row >> 11;
#pragma unroll
      for (int ni = 0; ni < 2; ++ni) {
        f32x4 v = acc[mi][ni];
        const int col = colb + ni * 16;
        const int which = col >> 10;
        const int h = (col >> 6) & 15;
        const int hd = col & 63;
        // Q pre-scale: 0.125 * log2(e) so attn softmax runs in exp2 domain
        const float s = (which == 0) ? 0.18033688011112042f : 1.0f;
        __bf16* dst = Oq + ((size_t)which * 64 + bidx * 16 + h) * (size_t)(2048 * 64) + hd;
#pragma unroll
        for (int i = 0; i < 4; ++i)
          dst[(size_t)((row + i) & 2047) * 64] = (__bf16)(v[i] * s);
      }
    }
  } else {
#pragma unroll
    for (int mi = 0; mi < 4; ++mi) {
      const int row = rowb + mi * 16;
#pragma unroll
      for (int ni = 0; ni < 2; ++ni) {
        const int col = colb + ni * 16;
        const float bv = bias[col];
        f32x4 v = acc[mi][ni];
#pragma unroll
        for (int i = 0; i < 4; ++i)
          Of[(size_t)(row + i) * 1024 + col] = v[i] + bv;
      }
    }
  }
}

// ---------------- flash attention (R10, verified: 117.5us) ----------------
// At its structural LDS-port roofline: MfmaUtil 31% == port cap for 20 MFMA : 16 b128-reads/iter.
__global__ __launch_bounds__(256) void mhsa_attn(const __bf16* __restrict__ QKV,
                                                 __bf16* __restrict__ Out) {
  const int tid = threadIdx.x;
  const int lane = tid & 63, w = tid >> 6;
  const int blk = blockIdx.x;           // blk = qt*64 + bh -> XCD(blk%8)=bh%8: KV L2-resident per XCD
  const int bh = blk & 63, qt = blk >> 6;
  const int lq = lane & 31, hi = lane >> 5;
  const int l7 = lane & 7, l3 = lane >> 3;

  const size_t bhoff = (size_t)bh * (2048 * 64);
  const __bf16* Qp = QKV + bhoff;
  const __bf16* Kp = QKV + (size_t)(64 * 2048 * 64) + bhoff;
  const __bf16* Vp = QKV + (size_t)(128 * 2048 * 64) + bhoff;

  __shared__ char smem[32768];  // 2 x {K [64][64] swz (8KB) | V^T [64][64] swz (8KB)}

  const int q0 = qt * 128 + w * 32;

  bf16x8 qf[4];
#pragma unroll
  for (int s = 0; s < 4; ++s)
    qf[s] = *(const bf16x8*)&Qp[(size_t)(q0 + lq) * 64 + s * 16 + hi * 8];

  // all-ones bf16 A-operand for the l-MFMA (layout-invariant)
  union { u32 wv[4]; bf16x8 v; } ou;
  ou.wv[0] = ou.wv[1] = ou.wv[2] = ou.wv[3] = 0x3F803F80u;
  const bf16x8 onesA = ou.v;

  f32x16 Oacc0 = 0.f, Oacc1 = 0.f;   // OT: col=lane&31=q, d(per 32-blk)=(r&3)+8*(r>>2)+4*hi
  f32x16 lacc = 0.f;                 // l accumulator: every row = sum_k P[k][q=lq]
  float m_run = -1e30f;

  const __bf16* Kg = Kp + (size_t)(w * 16 + l3) * 64 + ((l7 ^ l3) * 8);
  const int kldoff = w * 2048 + lane * 16;

  const int c8v = tid >> 5, k0v = (tid & 31) * 2;

  // ---- prologue: stage tile 0 into buf0 ----
  {
    async16(Kg, smem + kldoff);
    async16(Kg + 512, smem + kldoff + 1024);
    bf16x8 v0 = *(const bf16x8*)&Vp[(size_t)k0v * 64 + c8v * 8];
    bf16x8 v1 = *(const bf16x8*)&Vp[(size_t)(k0v + 1) * 64 + c8v * 8];
    char* Vb = smem + 8192;
#pragma unroll
    for (int j = 0; j < 8; ++j) {
      const int d = c8v * 8 + j;
      bf16x2 pr = { v0[j], v1[j] };
      *(bf16x2*)(Vb + ((d * 128 + k0v * 2) ^ ((d & 7) << 4))) = pr;
    }
  }
  __syncthreads();  // drains vmcnt -> K tile0 resident

  for (int t = 0; t < 32; ++t) {
    char* Kc = smem + (t & 1) * 16384;        // current K buffer
    char* Vc = Kc + 8192;                     // current V^T buffer
    char* Kn = smem + ((t & 1) ^ 1) * 16384;  // next K buffer
    char* Vn = Kn + 8192;

    // ---- issue-early: K async -> Kn (drains at end-of-iter barrier); V loads to regs ----
    bf16x8 v0n, v1n;
    const bool pf = (t < 31);
    if (pf) {
      const size_t ktn = (size_t)(t + 1) * 64;
      async16(Kg + ktn * 64, Kn + kldoff);
      async16(Kg + ktn * 64 + 512, Kn + kldoff + 1024);
      v0n = *(const bf16x8*)&Vp[(ktn + k0v) * 64 + c8v * 8];
      v1n = *(const bf16x8*)&Vp[(ktn + k0v + 1) * 64 + c8v * 8];
    }

    // ---- S^T = K Q^T : 8 MFMA (T5) ----
    f32x16 st0 = 0.f, st1 = 0.f;
    __builtin_amdgcn_s_setprio(1);
#pragma unroll
    for (int s = 0; s < 4; ++s) {
      bf16x8 kf = *(const bf16x8*)(Kc + lq * 128 + ((s * 32 + hi * 16) ^ (l7 << 4)));
      st0 = __builtin_amdgcn_mfma_f32_32x32x16_bf16(kf, qf[s], st0, 0, 0, 0);
    }
#pragma unroll
    for (int s = 0; s < 4; ++s) {
      bf16x8 kf = *(const bf16x8*)(Kc + (32 + lq) * 128 + ((s * 32 + hi * 16) ^ (l7 << 4)));
      st1 = __builtin_amdgcn_mfma_f32_32x32x16_bf16(kf, qf[s], st1, 0, 0, 0);
    }
    __builtin_amdgcn_s_setprio(0);

    // ---- online softmax, log2 domain ----
    f32x2 m2 = f32x2{ st0[0], st0[1] };
#pragma unroll
    for (int r = 1; r < 8; ++r) m2 = pkmax(m2, f32x2{ st0[2 * r], st0[2 * r + 1] });
#pragma unroll
    for (int r = 0; r < 8; ++r) m2 = pkmax(m2, f32x2{ st1[2 * r], st1[2 * r + 1] });
    float mx = xmax64(fmaxf(m2.x, m2.y));

    // defer-max (T13): rescale only when max grew past THR=8 (P bounded by 2^8)
    if (!__all(mx - m_run <= 8.f)) {
      const float mnew = fmaxf(m_run, mx);
      const float fs = exp2v(m_run - mnew);
      m_run = mnew;
#pragma unroll
      for (int r = 0; r < 16; ++r) { Oacc0[r] *= fs; Oacc1[r] *= fs; lacc[r] *= fs; }
    }

    // P = exp2(S - m_run)   (sum via l-MFMA below)
    const float mb = m_run;
#pragma unroll
    for (int r = 0; r < 16; ++r) st0[r] = exp2v(st0[r] - mb);
#pragma unroll
    for (int r = 0; r < 16; ++r) st1[r] = exp2v(st1[r] - mb);

    // ---- P -> bf16 B-operand frags in-register (T12) ----
    bf16x8 pa[4];
#pragma unroll
    for (int kb = 0; kb < 2; ++kb) {
      const f32x16& st = kb ? st1 : st0;
#pragma unroll
      for (int s16 = 0; s16 < 2; ++s16) {
        u32 A0 = cvtpk_bf16(st[8 * s16 + 0], st[8 * s16 + 1]);
        u32 B0 = cvtpk_bf16(st[8 * s16 + 4], st[8 * s16 + 5]);
        swap32(A0, B0);
        u32 A1 = cvtpk_bf16(st[8 * s16 + 2], st[8 * s16 + 3]);
        u32 B1 = cvtpk_bf16(st[8 * s16 + 6], st[8 * s16 + 7]);
        swap32(A1, B1);
        union { u32 wv[4]; bf16x8 v; } uu;
        uu.wv[0] = A0; uu.wv[1] = A1; uu.wv[2] = B0; uu.wv[3] = B1;
        pa[kb * 2 + s16] = uu.v;
      }
    }

    // ---- O^T += V^T P^T (8 MFMA) and l += ones . P^T (4 MFMA) (T5) ----
    __builtin_amdgcn_s_setprio(1);
#pragma unroll
    for (int ks = 0; ks < 4; ++ks) {
      bf16x8 vf = *(const bf16x8*)(Vc + lq * 128 + ((ks * 32 + hi * 16) ^ (l7 << 4)));
      Oacc0 = __builtin_amdgcn_mfma_f32_32x32x16_bf16(vf, pa[ks], Oacc0, 0, 0, 0);
      lacc = __builtin_amdgcn_mfma_f32_32x32x16_bf16(onesA, pa[ks], lacc, 0, 0, 0);
    }
#pragma unroll
    for (int ks = 0; ks < 4; ++ks) {
      bf16x8 vf = *(const bf16x8*)(Vc + (32 + lq) * 128 + ((ks * 32 + hi * 16) ^ (l7 << 4)));
      Oacc1 = __builtin_amdgcn_mfma_f32_32x32x16_bf16(vf, pa[ks], Oacc1, 0, 0, 0);
    }
    __builtin_amdgcn_s_setprio(0);

    // ---- write-late: V tile t+1 into the other buffer ----
    if (pf) {
#pragma unroll
      for (int j = 0; j < 8; ++j) {
        const int d = c8v * 8 + j;
        bf16x2 pr = { v0n[j], v1n[j] };
        *(bf16x2*)(Vn + ((d * 128 + k0v * 2) ^ ((d & 7) << 4))) = pr;
      }
    }
    __syncthreads();  // drains vmcnt (K async lands) + lgkm (V writes visible)
  }

  // ---- epilogue: lane (lq,hi) owns q=q0+lq, d = db*32 + rg*8 + hi*4 + 0..3 ----
  const float inv = 1.0f / lacc[0];   // every row of lacc = l(q=lq)
  const int b = bh >> 4, h = bh & 15;
  __bf16* orow = Out + ((size_t)(b * 2048 + q0 + lq)) * 1024 + h * 64;
#pragma unroll
  for (int db = 0; db < 2; ++db) {
    const f32x16& O = db ? Oacc1 : Oacc0;
#pragma unroll
    for (int rg = 0; rg < 4; ++rg) {
      u32 plo = cvtpk_bf16(O[rg * 4 + 0] * inv, O[rg * 4 + 1] * inv);
      u32 phi = cvtpk_bf16(O[rg * 4 + 2] * inv, O[rg * 4 + 3] * inv);
      u32x2 pk = { plo, phi };
      *(u32x2*)&orow[db * 32 + rg * 8 + hi * 4] = pk;
    }
  }
}

// ---------------- launcher ----------------
extern "C" void kernel_launch(void* const* d_in, const int* in_sizes, int n_in,
                              void* d_out, int out_size, void* d_ws, size_t ws_size,
                              hipStream_t stream) {
  const float* x  = (const float*)d_in[0];
  const float* wq = (const float*)d_in[1];
  const float* wp = (const float*)d_in[2];
  const float* bp = (const float*)d_in[3];
  char* ws = (char*)d_ws;

  __bf16* xo   = (__bf16*)(ws);               // 16 MB (reused as attn-out)
  __bf16* wqo  = (__bf16*)(ws + 16777216);
  __bf16* wpo  = (__bf16*)(ws + 23068672);
  __bf16* qkv  = (__bf16*)(ws + 25165824);    // 48 MB [3][64][2048][64]
  __bf16* aout = xo;
  float* y = (float*)d_out;

  cast_to_bf16<<<12288, 256, 0, stream>>>(x, wq, wp, xo, wqo, wpo);
  gemm_bt<0><<<dim3(64, 24), 512, 0, stream>>>(xo, wqo, qkv, nullptr, nullptr);
  mhsa_attn<<<1024, 256, 0, stream>>>(qkv, aout);
  gemm_bt<1><<<dim3(64, 8), 512, 0, stream>>>(aout, wpo, nullptr, y, bp);
}